// Round 13
// baseline (327.227 us; speedup 1.0000x reference)
//
#include <hip/hip_runtime.h>
#include <stdint.h>

#define NSIG   32768
#define NATOM  512
#define MDIM   64
#define SPAR   5
#define EPS    1e-10

typedef float f32x2 __attribute__((ext_vector_type(2)));

__device__ __forceinline__ f32x2 pkfma(f32x2 a, f32x2 b, f32x2 c) {
#if __has_builtin(__builtin_elementwise_fma)
  return __builtin_elementwise_fma(a, b, c);
#else
  asm("v_pk_fma_f32 %0, %1, %2, %0" : "+v"(c) : "v"(a), "v"(b));
  return c;
#endif
}

// ---- prep: fp64 norms; Dt32 [dim][atom] f32; Dd64 [atom][dim] f64;
// ----       rnrm = 1/(||d||^2+eps) f64
__global__ __launch_bounds__(512) void prep_kernel(const float* __restrict__ D,
                                                   float*  __restrict__ Dt32,
                                                   double* __restrict__ Dd64,
                                                   double* __restrict__ rnrm) {
  int n = threadIdx.x;                 // atom 0..511
  double ss = 0.0;
#pragma unroll 8
  for (int c = 0; c < MDIM; ++c) {
    double v = (double)D[c * NATOM + n];
    ss += v * v;
  }
  double norm = sqrt(ss);
  if (norm < 1e-10) norm = 1e-10;
  double s2 = 0.0;
#pragma unroll 8
  for (int c = 0; c < MDIM; ++c) {
    double v = (double)D[c * NATOM + n] / norm;
    Dd64[((size_t)n << 6) + c]  = v;
    Dt32[(size_t)c * NATOM + n] = (float)v;
    s2 += v * v;
  }
  rnrm[n] = 1.0 / (s2 + EPS);
}

// ---- Gram matrix in f32 (steers the f32 corr recursion only) ---------------
__global__ __launch_bounds__(512) void gram_kernel(const float* __restrict__ Dt32,
                                                   float* __restrict__ G32) {
  int i = blockIdx.x;
  int j = threadIdx.x;
  float s = 0.f;
#pragma unroll 8
  for (int c = 0; c < MDIM; ++c)
    s += Dt32[(size_t)c * NATOM + i] * Dt32[(size_t)c * NATOM + j];
  G32[(size_t)i * NATOM + j] = s;
}

// ---- repack: xw[l][c*32+b] = z_e[b][c][l], coalesced via LDS transpose -----
__global__ __launch_bounds__(256) void repack_kernel(const float* __restrict__ z_e,
                                                     float* __restrict__ xw) {
  __shared__ float t[32][33];
  const int c  = blockIdx.x & 63;
  const int l0 = (blockIdx.x >> 6) << 5;
  const int tr = threadIdx.x >> 5;       // 0..7
  const int tc = threadIdx.x & 31;
#pragma unroll
  for (int p = 0; p < 4; ++p) {
    int b = tr + p * 8;
    t[b][tc] = z_e[(size_t)b * 65536 + (size_t)c * 1024 + l0 + tc];
  }
  __syncthreads();
#pragma unroll
  for (int p = 0; p < 4; ++p) {
    int lr = tr + p * 8;
    xw[(size_t)(l0 + lr) * 2048 + c * 32 + tc] = t[tc][lr];
  }
}

// ---- unpack: z_dl[b][c][l] = xw[l][c*32+b] (xw holds z_dl values after omp) -
__global__ __launch_bounds__(256) void unpack_kernel(const float* __restrict__ xw,
                                                     float* __restrict__ z_dl) {
  __shared__ float t[32][33];
  const int c  = blockIdx.x & 63;
  const int l0 = (blockIdx.x >> 6) << 5;
  const int tr = threadIdx.x >> 5;       // 0..7
  const int tc = threadIdx.x & 31;
#pragma unroll
  for (int p = 0; p < 4; ++p) {
    int lr = tr + p * 8;                 // read coalesced in b (=tc)
    t[lr][tc] = xw[(size_t)(l0 + lr) * 2048 + c * 32 + tc];
  }
  __syncthreads();
#pragma unroll
  for (int p = 0; p < 4; ++p) {
    int b = tr + p * 8;                  // write coalesced in l (=tc)
    z_dl[(size_t)b * 65536 + (size_t)c * 1024 + l0 + tc] = t[tc][b];
  }
}

// ---- main OMP kernel: pk-f32 GEMM + f32 scan/Gram + fp64 refinement ---------
// block = 256 = 4 waves, 32 sigs/block (token l). Wave w owns sigs [8w,8w+8).
// Atom-map: lane owns atoms [lane*8,lane*8+8) (cor2[4][8] f32x2 pairs).
// Group-map: lane (gsi=lane>>3, lg=lane&7) holds fp64 residual dims
// [8lg,8lg+8) of signal w*8+gsi in registers (rr[8]).
__global__ __launch_bounds__(256, 4) void omp13_kernel(float* __restrict__ xw,
                                                       const float* __restrict__ Dt32,
                                                       const double* __restrict__ Dd64,
                                                       const double* __restrict__ rnrm,
                                                       const float* __restrict__ G32,
                                                       float* __restrict__ coeff,
                                                       double* __restrict__ partial) {
  __shared__ float  xs[2048];              // 8 KiB x f32 slice (later: zv values)
  __shared__ double s_al[SPAR][32];
  __shared__ int    s_sel[SPAR][32];
  __shared__ double s_red[4];

  const int tid  = threadIdx.x;
  const int w    = __builtin_amdgcn_readfirstlane(tid >> 6);
  const int lane = tid & 63;
  const int abase = lane << 3;             // atom-map
  const int gsi  = lane >> 3;              // group-map: signal within wave
  const int lg   = lane & 7;               // group-map: dim-oct
  const int sig  = (w << 3) + gsi;
  const int bid  = blockIdx.x;
  const int l    = ((bid & 7) << 7) | (bid >> 3);   // XCD swizzle (bijective)

  // ---- stage x slice into LDS (coalesced) ----
  {
    const float* src = xw + (size_t)l * 2048 + tid * 8;
    float4 v0 = *(const float4*)src;
    float4 v1 = *(const float4*)(src + 4);
    *(float4*)&xs[tid * 8]     = v0;
    *(float4*)&xs[tid * 8 + 4] = v1;
  }
  __syncthreads();

  f32x2 cor2[4][8];                        // [atom-pair][sig]
#pragma unroll
  for (int a2 = 0; a2 < 4; ++a2)
#pragma unroll
    for (int si = 0; si < 8; ++si) cor2[a2][si] = (f32x2){0.f, 0.f};

  // ---- phase 1: packed f32 register GEMM, 1-deep D prefetch, x from LDS ----
  {
    const float* dbase = Dt32 + abase;
    const int xo = w << 3;
    float4 dA = *(const float4*)dbase;
    float4 dB = *(const float4*)(dbase + 4);
    for (int k = 0; k < MDIM; ++k) {
      f32x2 dp[4] = {{dA.x, dA.y}, {dA.z, dA.w}, {dB.x, dB.y}, {dB.z, dB.w}};
      float4 xA = *(const float4*)&xs[k * 32 + xo];
      float4 xB = *(const float4*)&xs[k * 32 + xo + 4];
      if (k + 1 < MDIM) {
        const float* dn = dbase + (size_t)(k + 1) * NATOM;
        dA = *(const float4*)dn; dB = *(const float4*)(dn + 4);
      }
      float xv[8] = {xA.x, xA.y, xA.z, xA.w, xB.x, xB.y, xB.z, xB.w};
#pragma unroll
      for (int si = 0; si < 8; ++si) {
        f32x2 xq = {xv[si], xv[si]};
#pragma unroll
        for (int a2 = 0; a2 < 4; ++a2)
          cor2[a2][si] = pkfma(dp[a2], xq, cor2[a2][si]);
      }
    }
  }

  // ---- fp64 residual in registers (group-mapped) ----
  double rr[8];
#pragma unroll
  for (int j = 0; j < 8; ++j)
    rr[j] = (double)xs[(lg * 8 + j) * 32 + sig];

  unsigned long long mk = ~0ull;           // atom-map availability bit (a*8+si)

#pragma unroll 1
  for (int it = 0; it < SPAR; ++it) {
    // ---- f32 keyscan (atom-mapped) ----
    unsigned int kb[8];
#pragma unroll
    for (int si = 0; si < 8; ++si) {
      unsigned int best = 0;
#pragma unroll
      for (int a = 0; a < 8; ++a) {
        float cv = (a & 1) ? cor2[a >> 1][si].y : cor2[a >> 1][si].x;
        float ac = fabsf(cv);
        unsigned int enc = (unsigned int)(511 - (abase + a));
        unsigned int kv = (__float_as_uint(ac) & 0xFFFFFC00u) | enc;
        bool avail = (mk >> ((a << 3) + si)) & 1ull;
        kv = avail ? kv : enc;             // masked competes as value 0
        best = best > kv ? best : kv;
      }
      kb[si] = best;
    }
#pragma unroll
    for (int o = 1; o < 8; o <<= 1)
#pragma unroll
      for (int si = 0; si < 8; ++si) {
        unsigned int ok = __shfl_xor(kb[si], o);
        kb[si] = kb[si] > ok ? kb[si] : ok;
      }
    unsigned int kk = kb[0];
#pragma unroll
    for (int si = 1; si < 8; ++si) kk = ((lane & 7) == si) ? kb[si] : kk;
#pragma unroll
    for (int o = 8; o < 64; o <<= 1) {
      unsigned int ok = __shfl_xor(kk, o);
      kk = kk > ok ? kk : ok;
    }

    // ---- group-parallel fp64 winner dot (all 8 si at once) ----
    const unsigned int wkg = __shfl(kk, gsi);
    const int gig = 511 - (int)(wkg & 0x1FFu);
    double p;
    {
      const double2* dp = (const double2*)(Dd64 + ((size_t)gig << 6) + (lg << 3));
      double2 q0 = dp[0], q1 = dp[1], q2 = dp[2], q3 = dp[3];
      p = ((q0.x*rr[0] + q0.y*rr[1]) + (q1.x*rr[2] + q1.y*rr[3]))
        + ((q2.x*rr[4] + q2.y*rr[5]) + (q3.x*rr[6] + q3.y*rr[7]));
    }
    p += __shfl_xor(p, 1); p += __shfl_xor(p, 2); p += __shfl_xor(p, 4);
    unsigned long long bkey =
      ((unsigned long long)__double_as_longlong(fabs(p)) & ~0x3FFull)
      | (unsigned long long)(511 - gig);
    double bcor = p;
    int bgi = gig;

    // ---- pending extras mask (atom-mapped) ----
    unsigned long long pend = 0ull;
#pragma unroll
    for (int si = 0; si < 8; ++si) {
      unsigned int wks = __shfl(kk, si);
      int widx = 511 - (int)(wks & 0x1FFu);
      float thr = __uint_as_float(wks & 0xFFFFFC00u) * 0.999f;
#pragma unroll
      for (int a = 0; a < 8; ++a) {
        float cv = (a & 1) ? cor2[a >> 1][si].y : cor2[a >> 1][si].x;
        bool avail = (mk >> ((a << 3) + si)) & 1ull;
        bool inb = avail && (thr > 0.0f) && (fabsf(cv) >= thr)
                 && ((abase + a) != widx);
        pend |= inb ? (1ull << ((a << 3) + si)) : 0ull;
      }
    }
    // ---- rare: refine extras, one per si per pass (group-parallel dots) ----
    while (__any(pend != 0ull)) {
      int myext = -1;
#pragma unroll
      for (int si = 0; si < 8; ++si) {
        unsigned long long m8 = (pend >> si) & 0x0101010101010101ull;
        unsigned long long bal = __ballot(m8 != 0ull);
        int ge = -1;
        if (bal != 0ull) {
          int src = __ffsll((long long)bal) - 1;
          unsigned long long pm = __shfl(m8, src);
          int a0 = (__ffsll((long long)pm) - 1) >> 3;
          ge = (src << 3) + a0;
        }
        if (lane == si) myext = ge;
        if (ge >= 0 && (ge >> 3) == lane)
          pend &= ~(1ull << (((ge & 7) << 3) + si));
      }
      int gie = __shfl(myext, gsi);        // group-uniform
      if (gie >= 0) {
        const double2* dp = (const double2*)(Dd64 + ((size_t)gie << 6) + (lg << 3));
        double2 q0 = dp[0], q1 = dp[1], q2 = dp[2], q3 = dp[3];
        double pe = ((q0.x*rr[0] + q0.y*rr[1]) + (q1.x*rr[2] + q1.y*rr[3]))
                  + ((q2.x*rr[4] + q2.y*rr[5]) + (q3.x*rr[6] + q3.y*rr[7]));
        pe += __shfl_xor(pe, 1); pe += __shfl_xor(pe, 2); pe += __shfl_xor(pe, 4);
        unsigned long long ke =
          ((unsigned long long)__double_as_longlong(fabs(pe)) & ~0x3FFull)
          | (unsigned long long)(511 - gie);
        if (ke > bkey) { bkey = ke; bcor = pe; bgi = gie; }
      }
    }

    // ---- finalize winner per group ----
    double alpha = bcor * rnrm[bgi];
    if (lg == 0) { s_sel[it][sig] = bgi; s_al[it][sig] = alpha; }
#pragma unroll
    for (int si = 0; si < 8; ++si) {
      int gf = __shfl(bgi, si << 3);
      if ((gf >> 3) == lane) mk &= ~(1ull << (((gf & 7) << 3) + si));
    }

    // fp64 residual update EVERY iter (z_dl comes from rr at the end)
    {
      const double2* dp = (const double2*)(Dd64 + ((size_t)bgi << 6) + (lg << 3));
      double2 q0 = dp[0], q1 = dp[1], q2 = dp[2], q3 = dp[3];
      rr[0] -= alpha*q0.x; rr[1] -= alpha*q0.y;
      rr[2] -= alpha*q1.x; rr[3] -= alpha*q1.y;
      rr[4] -= alpha*q2.x; rr[5] -= alpha*q2.y;
      rr[6] -= alpha*q3.x; rr[7] -= alpha*q3.y;
    }

    if (it != SPAR - 1) {
      // packed f32 Gram recursion (atom-mapped), 2 sigs per batch
#pragma unroll
      for (int sb = 0; sb < 8; sb += 2) {
        int   g0i = __shfl(bgi, sb << 3);
        float a0f = (float)__shfl(alpha, sb << 3);
        int   g1i = __shfl(bgi, (sb + 1) << 3);
        float a1f = (float)__shfl(alpha, (sb + 1) << 3);
        const f32x2* gp0 = (const f32x2*)(G32 + (size_t)g0i * NATOM + abase);
        const f32x2* gp1 = (const f32x2*)(G32 + (size_t)g1i * NATOM + abase);
        f32x2 na0 = {-a0f, -a0f};
        f32x2 na1 = {-a1f, -a1f};
#pragma unroll
        for (int a2 = 0; a2 < 4; ++a2) {
          cor2[a2][sb]     = pkfma(gp0[a2], na0, cor2[a2][sb]);
          cor2[a2][sb + 1] = pkfma(gp1[a2], na1, cor2[a2][sb + 1]);
        }
      }
    }
  }
  __syncthreads();                         // publish s_sel/s_al; xs reads done

  // ---- epilogue A: zv = f32(x - rr) into xs (own slots) + loss ----
  {
    double s2 = 0.0;
    const int d0 = lg << 3;
#pragma unroll
    for (int j = 0; j < 8; ++j) {
      int idx = (d0 + j) * 32 + sig;
      double x = (double)xs[idx];
      float zv = (float)(x - rr[j]);
      xs[idx] = zv;                        // single-owner slot, no race
      double diff = (double)zv - x;
      s2 += diff * diff;
    }
#pragma unroll
    for (int o = 1; o < 64; o <<= 1) s2 += __shfl_xor(s2, o);
    if (lane == 0) s_red[w] = s2;
  }

  // ---- epilogue B part 1: coeff zero-fill (coalesced 128B runs) ----
  {
    const float4 z4 = make_float4(0.f, 0.f, 0.f, 0.f);
#pragma unroll
    for (int p2 = 0; p2 < 16; ++p2) {
      int idx = tid + (p2 << 8);           // 0..4095 = atom*8 + quad
      int a = idx >> 3, q = idx & 7;
      *(float4*)(coeff + (size_t)a * NSIG + ((size_t)l << 5) + (q << 2)) = z4;
    }
  }
  __syncthreads();                         // zv in xs ready; zeros ordered

  // ---- epilogue C: coalesced zv write-back into xw slice (in-place safe) ----
  {
    float* dst = xw + (size_t)l * 2048 + tid * 8;
    float4 v0 = *(const float4*)&xs[tid * 8];
    float4 v1 = *(const float4*)&xs[tid * 8 + 4];
    *(float4*)dst       = v0;
    *(float4*)(dst + 4) = v1;
  }
  if (tid == 0) partial[bid] = (s_red[0] + s_red[1]) + (s_red[2] + s_red[3]);
  if (tid < 32) {
#pragma unroll
    for (int tt = 0; tt < SPAR; ++tt) {
      int gi = s_sel[tt][tid];
      coeff[(size_t)gi * NSIG + ((size_t)l << 5) + tid] = (float)s_al[tt][tid];
    }
  }
}

// ---- finalize loss ---------------------------------------------------------
__global__ __launch_bounds__(64) void finalize_kernel(const double* __restrict__ partial,
                                                      float* __restrict__ loss_out) {
  double s = 0.0;
  for (int i = threadIdx.x; i < 1024; i += 64) s += partial[i];
#pragma unroll
  for (int o = 32; o > 0; o >>= 1) s += __shfl_down(s, o);
  if (threadIdx.x == 0) loss_out[0] = (float)(1.25 * s / 2097152.0);
}

extern "C" void kernel_launch(void* const* d_in, const int* in_sizes, int n_in,
                              void* d_out, int out_size, void* d_ws, size_t ws_size,
                              hipStream_t stream) {
  const float* z_e = (const float*)d_in[0];
  const float* D   = (const float*)d_in[1];

  float* out      = (float*)d_out;
  float* z_dl     = out;                       // 2097152 elems
  float* loss_out = out + 2097152;             // 1 elem
  float* coeff    = out + 2097153;             // 512*32768 elems

  char*   ws      = (char*)d_ws;
  double* partial = (double*)ws;                               // 8 KiB (1024)
  float*  Dt32    = (float*) (ws + 8192);                      // 128 KiB
  double* Dd64    = (double*)(ws + 8192 + 131072);             // 256 KiB
  double* rnrm    = (double*)(ws + 8192 + 131072 + 262144);    // 4 KiB
  float*  G32     = (float*) (ws + 8192 + 131072 + 262144 + 4096);           // 1 MiB
  float*  xw      = (float*) (ws + 8192 + 131072 + 262144 + 4096 + 1048576); // 8 MiB

  prep_kernel<<<1, 512, 0, stream>>>(D, Dt32, Dd64, rnrm);
  gram_kernel<<<NATOM, NATOM, 0, stream>>>(Dt32, G32);
  repack_kernel<<<2048, 256, 0, stream>>>(z_e, xw);
  omp13_kernel<<<1024, 256, 0, stream>>>(xw, Dt32, Dd64, rnrm, G32, coeff, partial);
  unpack_kernel<<<2048, 256, 0, stream>>>(xw, z_dl);
  finalize_kernel<<<1, 64, 0, stream>>>(partial, loss_out);
}

// Round 15
// 150.509 us; speedup vs baseline: 2.1741x; 2.1741x over previous
//
#include <hip/hip_runtime.h>
#include <stdint.h>

#define NSIG   32768
#define NATOM  512
#define MDIM   64
#define SPAR   5
#define EPS    1e-10

typedef float f32x4n __attribute__((ext_vector_type(4)));   // native vec for nt-store

// ---- prep: fp64 norms; Dt32 [dim][atom] f32; Dd64 [atom][dim] f64;
// ----       rnrm = 1/(||d||^2+eps) f64
__global__ __launch_bounds__(512) void prep_kernel(const float* __restrict__ D,
                                                   float*  __restrict__ Dt32,
                                                   double* __restrict__ Dd64,
                                                   double* __restrict__ rnrm) {
  int n = threadIdx.x;                 // atom 0..511
  double ss = 0.0;
#pragma unroll 8
  for (int c = 0; c < MDIM; ++c) {
    double v = (double)D[c * NATOM + n];
    ss += v * v;
  }
  double norm = sqrt(ss);
  if (norm < 1e-10) norm = 1e-10;
  double s2 = 0.0;
#pragma unroll 8
  for (int c = 0; c < MDIM; ++c) {
    double v = (double)D[c * NATOM + n] / norm;
    Dd64[((size_t)n << 6) + c]  = v;
    Dt32[(size_t)c * NATOM + n] = (float)v;
    s2 += v * v;
  }
  rnrm[n] = 1.0 / (s2 + EPS);
}

// ---- Gram matrix in f32 (steers the f32 corr recursion only) ---------------
__global__ __launch_bounds__(512) void gram_kernel(const float* __restrict__ Dt32,
                                                   float* __restrict__ G32) {
  int i = blockIdx.x;
  int j = threadIdx.x;
  float s = 0.f;
#pragma unroll 8
  for (int c = 0; c < MDIM; ++c)
    s += Dt32[(size_t)c * NATOM + i] * Dt32[(size_t)c * NATOM + j];
  G32[(size_t)i * NATOM + j] = s;
}

// ---- repack: xw[l][c*32+b] = z_e[b][c][l], coalesced via LDS transpose -----
__global__ __launch_bounds__(256) void repack_kernel(const float* __restrict__ z_e,
                                                     float* __restrict__ xw) {
  __shared__ float t[32][33];
  const int c  = blockIdx.x & 63;
  const int l0 = (blockIdx.x >> 6) << 5;
  const int tr = threadIdx.x >> 5;       // 0..7
  const int tc = threadIdx.x & 31;
#pragma unroll
  for (int p = 0; p < 4; ++p) {
    int b = tr + p * 8;
    t[b][tc] = z_e[(size_t)b * 65536 + (size_t)c * 1024 + l0 + tc];
  }
  __syncthreads();
#pragma unroll
  for (int p = 0; p < 4; ++p) {
    int lr = tr + p * 8;
    xw[(size_t)(l0 + lr) * 2048 + c * 32 + tc] = t[tc][lr];
  }
}

// ---- unpack: z_dl[b][c][l] = xw[l][c*32+b] (xw holds z_dl values after omp) -
__global__ __launch_bounds__(256) void unpack_kernel(const float* __restrict__ xw,
                                                     float* __restrict__ z_dl) {
  __shared__ float t[32][33];
  const int c  = blockIdx.x & 63;
  const int l0 = (blockIdx.x >> 6) << 5;
  const int tr = threadIdx.x >> 5;       // 0..7
  const int tc = threadIdx.x & 31;
#pragma unroll
  for (int p = 0; p < 4; ++p) {
    int lr = tr + p * 8;                 // read coalesced in b (=tc)
    t[lr][tc] = xw[(size_t)(l0 + lr) * 2048 + c * 32 + tc];
  }
  __syncthreads();
#pragma unroll
  for (int p = 0; p < 4; ++p) {
    int b = tr + p * 8;                  // write coalesced in l (=tc)
    z_dl[(size_t)b * 65536 + (size_t)c * 1024 + l0 + tc] = t[tc][b];
  }
}

// ---- main OMP kernel: f32 GEMM/scan/Gram + group-parallel fp64 refinement ---
// block = 256 = 4 waves, 32 sigs/block (token l). Wave w owns sigs [8w,8w+8).
// Atom-map: lane owns atoms [lane*8,lane*8+8) (cor[8][8] f32).
// Group-map: lane (gsi=lane>>3, lg=lane&7) holds fp64 residual dims
// [8lg,8lg+8) of signal w*8+gsi in registers (rr[8]).
__global__ __launch_bounds__(256) void omp14_kernel(float* __restrict__ xw,
                                                    const float* __restrict__ Dt32,
                                                    const double* __restrict__ Dd64,
                                                    const double* __restrict__ rnrm,
                                                    const float* __restrict__ G32,
                                                    float* __restrict__ coeff,
                                                    double* __restrict__ partial) {
  __shared__ float  xs[2048];              // 8 KiB x f32 slice (later: zv values)
  __shared__ double s_al[SPAR][32];
  __shared__ int    s_sel[SPAR][32];
  __shared__ double s_red[4];

  const int tid  = threadIdx.x;
  const int w    = __builtin_amdgcn_readfirstlane(tid >> 6);
  const int lane = tid & 63;
  const int abase = lane << 3;             // atom-map
  const int gsi  = lane >> 3;              // group-map: signal within wave
  const int lg   = lane & 7;               // group-map: dim-oct
  const int sig  = (w << 3) + gsi;
  const int bid  = blockIdx.x;
  const int l    = ((bid & 7) << 7) | (bid >> 3);   // XCD swizzle (bijective)

  // ---- stage x slice into LDS (coalesced) ----
  {
    const float* src = xw + (size_t)l * 2048 + tid * 8;
    float4 v0 = *(const float4*)src;
    float4 v1 = *(const float4*)(src + 4);
    *(float4*)&xs[tid * 8]     = v0;
    *(float4*)&xs[tid * 8 + 4] = v1;
  }
  __syncthreads();

  float cor[8][8];                         // [atom][sig] f32
#pragma unroll
  for (int a = 0; a < 8; ++a)
#pragma unroll
    for (int si = 0; si < 8; ++si) cor[a][si] = 0.0f;

  // ---- phase 1: f32 register GEMM, 2-deep D prefetch, x broadcast from LDS --
  {
    const float* dbase = Dt32 + abase;
    const int xo = w << 3;
    float4 dA0 = *(const float4*)dbase;
    float4 dB0 = *(const float4*)(dbase + 4);
    float4 dA1 = *(const float4*)(dbase + NATOM);
    float4 dB1 = *(const float4*)(dbase + NATOM + 4);
    for (int k = 0; k < MDIM; k += 2) {
      float4 xA0 = *(const float4*)&xs[k * 32 + xo];
      float4 xB0 = *(const float4*)&xs[k * 32 + xo + 4];
      float4 xA1 = *(const float4*)&xs[(k + 1) * 32 + xo];
      float4 xB1 = *(const float4*)&xs[(k + 1) * 32 + xo + 4];
      float dv0[8] = {dA0.x, dA0.y, dA0.z, dA0.w, dB0.x, dB0.y, dB0.z, dB0.w};
      float xv0[8] = {xA0.x, xA0.y, xA0.z, xA0.w, xB0.x, xB0.y, xB0.z, xB0.w};
      float dv1[8] = {dA1.x, dA1.y, dA1.z, dA1.w, dB1.x, dB1.y, dB1.z, dB1.w};
      float xv1[8] = {xA1.x, xA1.y, xA1.z, xA1.w, xB1.x, xB1.y, xB1.z, xB1.w};
      if (k + 2 < MDIM) {
        const float* dn = dbase + (size_t)(k + 2) * NATOM;
        dA0 = *(const float4*)dn; dB0 = *(const float4*)(dn + 4);
        const float* dm = dbase + (size_t)(k + 3) * NATOM;
        dA1 = *(const float4*)dm; dB1 = *(const float4*)(dm + 4);
      }
#pragma unroll
      for (int a = 0; a < 8; ++a)
#pragma unroll
        for (int si = 0; si < 8; ++si)
          cor[a][si] += dv0[a] * xv0[si];
#pragma unroll
      for (int a = 0; a < 8; ++a)
#pragma unroll
        for (int si = 0; si < 8; ++si)
          cor[a][si] += dv1[a] * xv1[si];
    }
  }

  // ---- fp64 residual in registers (group-mapped) ----
  double rr[8];
#pragma unroll
  for (int j = 0; j < 8; ++j)
    rr[j] = (double)xs[(lg * 8 + j) * 32 + sig];

  unsigned long long mk = ~0ull;           // atom-map availability bit (a*8+si)

#pragma unroll 1
  for (int it = 0; it < SPAR; ++it) {
    // ---- f32 keyscan (atom-mapped) ----
    unsigned int kb[8];
#pragma unroll
    for (int si = 0; si < 8; ++si) {
      unsigned int best = 0;
#pragma unroll
      for (int a = 0; a < 8; ++a) {
        float ac = fabsf(cor[a][si]);
        unsigned int enc = (unsigned int)(511 - (abase + a));
        unsigned int kv = (__float_as_uint(ac) & 0xFFFFFC00u) | enc;
        bool avail = (mk >> ((a << 3) + si)) & 1ull;
        kv = avail ? kv : enc;             // masked competes as value 0
        best = best > kv ? best : kv;
      }
      kb[si] = best;
    }
#pragma unroll
    for (int o = 1; o < 8; o <<= 1)
#pragma unroll
      for (int si = 0; si < 8; ++si) {
        unsigned int ok = __shfl_xor(kb[si], o);
        kb[si] = kb[si] > ok ? kb[si] : ok;
      }
    unsigned int kk = kb[0];
#pragma unroll
    for (int si = 1; si < 8; ++si) kk = ((lane & 7) == si) ? kb[si] : kk;
#pragma unroll
    for (int o = 8; o < 64; o <<= 1) {
      unsigned int ok = __shfl_xor(kk, o);
      kk = kk > ok ? kk : ok;
    }

    // ---- group-parallel fp64 winner dot (all 8 si at once) ----
    const unsigned int wkg = __shfl(kk, gsi);
    const int gig = 511 - (int)(wkg & 0x1FFu);
    double p;
    {
      const double2* dp = (const double2*)(Dd64 + ((size_t)gig << 6) + (lg << 3));
      double2 q0 = dp[0], q1 = dp[1], q2 = dp[2], q3 = dp[3];
      p = ((q0.x*rr[0] + q0.y*rr[1]) + (q1.x*rr[2] + q1.y*rr[3]))
        + ((q2.x*rr[4] + q2.y*rr[5]) + (q3.x*rr[6] + q3.y*rr[7]));
    }
    p += __shfl_xor(p, 1); p += __shfl_xor(p, 2); p += __shfl_xor(p, 4);
    unsigned long long bkey =
      ((unsigned long long)__double_as_longlong(fabs(p)) & ~0x3FFull)
      | (unsigned long long)(511 - gig);
    double bcor = p;
    int bgi = gig;

    // ---- pending extras mask (atom-mapped) ----
    unsigned long long pend = 0ull;
#pragma unroll
    for (int si = 0; si < 8; ++si) {
      unsigned int wks = __shfl(kk, si);
      int widx = 511 - (int)(wks & 0x1FFu);
      float thr = __uint_as_float(wks & 0xFFFFFC00u) * 0.999f;
#pragma unroll
      for (int a = 0; a < 8; ++a) {
        bool avail = (mk >> ((a << 3) + si)) & 1ull;
        bool inb = avail && (thr > 0.0f) && (fabsf(cor[a][si]) >= thr)
                 && ((abase + a) != widx);
        pend |= inb ? (1ull << ((a << 3) + si)) : 0ull;
      }
    }
    // ---- rare: refine extras, one per si per pass (group-parallel dots) ----
    while (__any(pend != 0ull)) {
      int myext = -1;
#pragma unroll
      for (int si = 0; si < 8; ++si) {
        unsigned long long m8 = (pend >> si) & 0x0101010101010101ull;
        unsigned long long bal = __ballot(m8 != 0ull);
        int ge = -1;
        if (bal != 0ull) {
          int src = __ffsll((long long)bal) - 1;
          unsigned long long pm = __shfl(m8, src);
          int a0 = (__ffsll((long long)pm) - 1) >> 3;
          ge = (src << 3) + a0;
        }
        if (lane == si) myext = ge;
        if (ge >= 0 && (ge >> 3) == lane)
          pend &= ~(1ull << (((ge & 7) << 3) + si));
      }
      int gie = __shfl(myext, gsi);        // group-uniform
      if (gie >= 0) {
        const double2* dp = (const double2*)(Dd64 + ((size_t)gie << 6) + (lg << 3));
        double2 q0 = dp[0], q1 = dp[1], q2 = dp[2], q3 = dp[3];
        double pe = ((q0.x*rr[0] + q0.y*rr[1]) + (q1.x*rr[2] + q1.y*rr[3]))
                  + ((q2.x*rr[4] + q2.y*rr[5]) + (q3.x*rr[6] + q3.y*rr[7]));
        pe += __shfl_xor(pe, 1); pe += __shfl_xor(pe, 2); pe += __shfl_xor(pe, 4);
        unsigned long long ke =
          ((unsigned long long)__double_as_longlong(fabs(pe)) & ~0x3FFull)
          | (unsigned long long)(511 - gie);
        if (ke > bkey) { bkey = ke; bcor = pe; bgi = gie; }
      }
    }

    // ---- finalize winner per group ----
    double alpha = bcor * rnrm[bgi];
    if (lg == 0) { s_sel[it][sig] = bgi; s_al[it][sig] = alpha; }
#pragma unroll
    for (int si = 0; si < 8; ++si) {
      int gf = __shfl(bgi, si << 3);
      if ((gf >> 3) == lane) mk &= ~(1ull << (((gf & 7) << 3) + si));
    }

    // fp64 residual update EVERY iter (z_dl comes from rr at the end)
    {
      const double2* dp = (const double2*)(Dd64 + ((size_t)bgi << 6) + (lg << 3));
      double2 q0 = dp[0], q1 = dp[1], q2 = dp[2], q3 = dp[3];
      rr[0] -= alpha*q0.x; rr[1] -= alpha*q0.y;
      rr[2] -= alpha*q1.x; rr[3] -= alpha*q1.y;
      rr[4] -= alpha*q2.x; rr[5] -= alpha*q2.y;
      rr[6] -= alpha*q3.x; rr[7] -= alpha*q3.y;
    }

    if (it != SPAR - 1) {
      // f32 Gram recursion (atom-mapped), 2 sigs per batch (register-lean)
#pragma unroll
      for (int sb = 0; sb < 8; sb += 2) {
        int   g0i = __shfl(bgi, sb << 3);
        float a0f = (float)__shfl(alpha, sb << 3);
        int   g1i = __shfl(bgi, (sb + 1) << 3);
        float a1f = (float)__shfl(alpha, (sb + 1) << 3);
        const float* gp0 = G32 + (size_t)g0i * NATOM + abase;
        const float* gp1 = G32 + (size_t)g1i * NATOM + abase;
        float4 u0 = *(const float4*)gp0;
        float4 u1 = *(const float4*)(gp0 + 4);
        float4 v0 = *(const float4*)gp1;
        float4 v1 = *(const float4*)(gp1 + 4);
        cor[0][sb] -= a0f*u0.x; cor[1][sb] -= a0f*u0.y;
        cor[2][sb] -= a0f*u0.z; cor[3][sb] -= a0f*u0.w;
        cor[4][sb] -= a0f*u1.x; cor[5][sb] -= a0f*u1.y;
        cor[6][sb] -= a0f*u1.z; cor[7][sb] -= a0f*u1.w;
        cor[0][sb+1] -= a1f*v0.x; cor[1][sb+1] -= a1f*v0.y;
        cor[2][sb+1] -= a1f*v0.z; cor[3][sb+1] -= a1f*v0.w;
        cor[4][sb+1] -= a1f*v1.x; cor[5][sb+1] -= a1f*v1.y;
        cor[6][sb+1] -= a1f*v1.z; cor[7][sb+1] -= a1f*v1.w;
      }
    }
  }
  __syncthreads();                         // publish s_sel/s_al; xs reads done

  // ---- epilogue A: zv = f32(x - rr) into xs (own slots) + loss ----
  {
    double s2 = 0.0;
    const int d0 = lg << 3;
#pragma unroll
    for (int j = 0; j < 8; ++j) {
      int idx = (d0 + j) * 32 + sig;
      double x = (double)xs[idx];
      float zv = (float)(x - rr[j]);
      xs[idx] = zv;                        // single-owner slot, no race
      double diff = (double)zv - x;
      s2 += diff * diff;
    }
#pragma unroll
    for (int o = 1; o < 64; o <<= 1) s2 += __shfl_xor(s2, o);
    if (lane == 0) s_red[w] = s2;
  }

  // ---- epilogue B part 1: coeff zero-fill (coalesced, nontemporal) ----
  {
    const f32x4n z4 = {0.f, 0.f, 0.f, 0.f};
#pragma unroll
    for (int p2 = 0; p2 < 16; ++p2) {
      int idx = tid + (p2 << 8);           // 0..4095 = atom*8 + quad
      int a = idx >> 3, q = idx & 7;
      __builtin_nontemporal_store(z4,
        (f32x4n*)(coeff + (size_t)a * NSIG + ((size_t)l << 5) + (q << 2)));
    }
  }
  __syncthreads();                         // zv in xs ready; zeros ordered

  // ---- epilogue C: coalesced zv write-back into xw slice (in-place safe) ----
  {
    float* dst = xw + (size_t)l * 2048 + tid * 8;
    float4 v0 = *(const float4*)&xs[tid * 8];
    float4 v1 = *(const float4*)&xs[tid * 8 + 4];
    *(float4*)dst       = v0;
    *(float4*)(dst + 4) = v1;
  }
  if (tid == 0) partial[bid] = (s_red[0] + s_red[1]) + (s_red[2] + s_red[3]);
  if (tid < 32) {
#pragma unroll
    for (int tt = 0; tt < SPAR; ++tt) {
      int gi = s_sel[tt][tid];
      coeff[(size_t)gi * NSIG + ((size_t)l << 5) + tid] = (float)s_al[tt][tid];
    }
  }
}

// ---- finalize loss ---------------------------------------------------------
__global__ __launch_bounds__(64) void finalize_kernel(const double* __restrict__ partial,
                                                      float* __restrict__ loss_out) {
  double s = 0.0;
  for (int i = threadIdx.x; i < 1024; i += 64) s += partial[i];
#pragma unroll
  for (int o = 32; o > 0; o >>= 1) s += __shfl_down(s, o);
  if (threadIdx.x == 0) loss_out[0] = (float)(1.25 * s / 2097152.0);
}

extern "C" void kernel_launch(void* const* d_in, const int* in_sizes, int n_in,
                              void* d_out, int out_size, void* d_ws, size_t ws_size,
                              hipStream_t stream) {
  const float* z_e = (const float*)d_in[0];
  const float* D   = (const float*)d_in[1];

  float* out      = (float*)d_out;
  float* z_dl     = out;                       // 2097152 elems
  float* loss_out = out + 2097152;             // 1 elem
  float* coeff    = out + 2097153;             // 512*32768 elems

  char*   ws      = (char*)d_ws;
  double* partial = (double*)ws;                               // 8 KiB (1024)
  float*  Dt32    = (float*) (ws + 8192);                      // 128 KiB
  double* Dd64    = (double*)(ws + 8192 + 131072);             // 256 KiB
  double* rnrm    = (double*)(ws + 8192 + 131072 + 262144);    // 4 KiB
  float*  G32     = (float*) (ws + 8192 + 131072 + 262144 + 4096);           // 1 MiB
  float*  xw      = (float*) (ws + 8192 + 131072 + 262144 + 4096 + 1048576); // 8 MiB

  prep_kernel<<<1, 512, 0, stream>>>(D, Dt32, Dd64, rnrm);
  gram_kernel<<<NATOM, NATOM, 0, stream>>>(Dt32, G32);
  repack_kernel<<<2048, 256, 0, stream>>>(z_e, xw);
  omp14_kernel<<<1024, 256, 0, stream>>>(xw, Dt32, Dd64, rnrm, G32, coeff, partial);
  unpack_kernel<<<2048, 256, 0, stream>>>(xw, z_dl);
  finalize_kernel<<<1, 64, 0, stream>>>(partial, loss_out);
}

// Round 16
// 135.117 us; speedup vs baseline: 2.4218x; 1.1139x over previous
//
#include <hip/hip_runtime.h>
#include <stdint.h>

#define NSIG   32768
#define NATOM  512
#define MDIM   64
#define SPAR   5
#define EPS    1e-10

// ---- prep: fp64 norms; Dt32 [dim][atom] f32; Dd64 [atom][dim] f64;
// ----       rnrm = 1/(||d||^2+eps) f64
__global__ __launch_bounds__(512) void prep_kernel(const float* __restrict__ D,
                                                   float*  __restrict__ Dt32,
                                                   double* __restrict__ Dd64,
                                                   double* __restrict__ rnrm) {
  int n = threadIdx.x;                 // atom 0..511
  double ss = 0.0;
#pragma unroll 8
  for (int c = 0; c < MDIM; ++c) {
    double v = (double)D[c * NATOM + n];
    ss += v * v;
  }
  double norm = sqrt(ss);
  if (norm < 1e-10) norm = 1e-10;
  double s2 = 0.0;
#pragma unroll 8
  for (int c = 0; c < MDIM; ++c) {
    double v = (double)D[c * NATOM + n] / norm;
    Dd64[((size_t)n << 6) + c]  = v;
    Dt32[(size_t)c * NATOM + n] = (float)v;
    s2 += v * v;
  }
  rnrm[n] = 1.0 / (s2 + EPS);
}

// ---- Gram matrix in f32 (steers the f32 corr recursion only) ---------------
__global__ __launch_bounds__(512) void gram_kernel(const float* __restrict__ Dt32,
                                                   float* __restrict__ G32) {
  int i = blockIdx.x;
  int j = threadIdx.x;
  float s = 0.f;
#pragma unroll 8
  for (int c = 0; c < MDIM; ++c)
    s += Dt32[(size_t)c * NATOM + i] * Dt32[(size_t)c * NATOM + j];
  G32[(size_t)i * NATOM + j] = s;
}

// ---- repack: xw[l][c*32+b] = z_e[b][c][l], coalesced via LDS transpose -----
__global__ __launch_bounds__(256) void repack_kernel(const float* __restrict__ z_e,
                                                     float* __restrict__ xw) {
  __shared__ float t[32][33];
  const int c  = blockIdx.x & 63;
  const int l0 = (blockIdx.x >> 6) << 5;
  const int tr = threadIdx.x >> 5;       // 0..7
  const int tc = threadIdx.x & 31;
#pragma unroll
  for (int p = 0; p < 4; ++p) {
    int b = tr + p * 8;
    t[b][tc] = z_e[(size_t)b * 65536 + (size_t)c * 1024 + l0 + tc];
  }
  __syncthreads();
#pragma unroll
  for (int p = 0; p < 4; ++p) {
    int lr = tr + p * 8;
    xw[(size_t)(l0 + lr) * 2048 + c * 32 + tc] = t[tc][lr];
  }
}

// ---- unpack: z_dl[b][c][l] = xw[l][c*32+b] (xw holds z_dl values after omp) -
__global__ __launch_bounds__(256) void unpack_kernel(const float* __restrict__ xw,
                                                     float* __restrict__ z_dl) {
  __shared__ float t[32][33];
  const int c  = blockIdx.x & 63;
  const int l0 = (blockIdx.x >> 6) << 5;
  const int tr = threadIdx.x >> 5;       // 0..7
  const int tc = threadIdx.x & 31;
#pragma unroll
  for (int p = 0; p < 4; ++p) {
    int lr = tr + p * 8;                 // read coalesced in b (=tc)
    t[lr][tc] = xw[(size_t)(l0 + lr) * 2048 + c * 32 + tc];
  }
  __syncthreads();
#pragma unroll
  for (int p = 0; p < 4; ++p) {
    int b = tr + p * 8;                  // write coalesced in l (=tc)
    z_dl[(size_t)b * 65536 + (size_t)c * 1024 + l0 + tc] = t[tc][b];
  }
}

// ---- main OMP kernel: f32 GEMM/scan/Gram + group-parallel fp64 refinement ---
// block = 256 = 4 waves, 32 sigs/block (token l). Wave w owns sigs [8w,8w+8).
// Atom-map: lane owns atoms [lane*8,lane*8+8) (cor[8][8] f32).
// Group-map: lane (gsi=lane>>3, lg=lane&7) holds fp64 residual dims
// [8lg,8lg+8) of signal w*8+gsi in registers (rr[8]).
__global__ __launch_bounds__(256) void omp12_kernel(float* __restrict__ xw,
                                                    const float* __restrict__ Dt32,
                                                    const double* __restrict__ Dd64,
                                                    const double* __restrict__ rnrm,
                                                    const float* __restrict__ G32,
                                                    float* __restrict__ coeff,
                                                    double* __restrict__ partial) {
  __shared__ float  xs[2048];              // 8 KiB x f32 slice (later: zv values)
  __shared__ double s_al[SPAR][32];
  __shared__ int    s_sel[SPAR][32];
  __shared__ double s_red[4];

  const int tid  = threadIdx.x;
  const int w    = __builtin_amdgcn_readfirstlane(tid >> 6);
  const int lane = tid & 63;
  const int abase = lane << 3;             // atom-map
  const int gsi  = lane >> 3;              // group-map: signal within wave
  const int lg   = lane & 7;               // group-map: dim-oct
  const int sig  = (w << 3) + gsi;
  const int bid  = blockIdx.x;
  const int l    = ((bid & 7) << 7) | (bid >> 3);   // XCD swizzle (bijective)

  // ---- stage x slice into LDS (coalesced) ----
  {
    const float* src = xw + (size_t)l * 2048 + tid * 8;
    float4 v0 = *(const float4*)src;
    float4 v1 = *(const float4*)(src + 4);
    *(float4*)&xs[tid * 8]     = v0;
    *(float4*)&xs[tid * 8 + 4] = v1;
  }
  __syncthreads();

  float cor[8][8];                         // [atom][sig] f32
#pragma unroll
  for (int a = 0; a < 8; ++a)
#pragma unroll
    for (int si = 0; si < 8; ++si) cor[a][si] = 0.0f;

  // ---- phase 1: f32 register GEMM, 2-deep D prefetch, x broadcast from LDS --
  {
    const float* dbase = Dt32 + abase;
    const int xo = w << 3;
    float4 dA0 = *(const float4*)dbase;
    float4 dB0 = *(const float4*)(dbase + 4);
    float4 dA1 = *(const float4*)(dbase + NATOM);
    float4 dB1 = *(const float4*)(dbase + NATOM + 4);
    for (int k = 0; k < MDIM; k += 2) {
      float4 xA0 = *(const float4*)&xs[k * 32 + xo];
      float4 xB0 = *(const float4*)&xs[k * 32 + xo + 4];
      float4 xA1 = *(const float4*)&xs[(k + 1) * 32 + xo];
      float4 xB1 = *(const float4*)&xs[(k + 1) * 32 + xo + 4];
      float dv0[8] = {dA0.x, dA0.y, dA0.z, dA0.w, dB0.x, dB0.y, dB0.z, dB0.w};
      float xv0[8] = {xA0.x, xA0.y, xA0.z, xA0.w, xB0.x, xB0.y, xB0.z, xB0.w};
      float dv1[8] = {dA1.x, dA1.y, dA1.z, dA1.w, dB1.x, dB1.y, dB1.z, dB1.w};
      float xv1[8] = {xA1.x, xA1.y, xA1.z, xA1.w, xB1.x, xB1.y, xB1.z, xB1.w};
      if (k + 2 < MDIM) {
        const float* dn = dbase + (size_t)(k + 2) * NATOM;
        dA0 = *(const float4*)dn; dB0 = *(const float4*)(dn + 4);
        const float* dm = dbase + (size_t)(k + 3) * NATOM;
        dA1 = *(const float4*)dm; dB1 = *(const float4*)(dm + 4);
      }
#pragma unroll
      for (int a = 0; a < 8; ++a)
#pragma unroll
        for (int si = 0; si < 8; ++si)
          cor[a][si] += dv0[a] * xv0[si];
#pragma unroll
      for (int a = 0; a < 8; ++a)
#pragma unroll
        for (int si = 0; si < 8; ++si)
          cor[a][si] += dv1[a] * xv1[si];
    }
  }

  // ---- fp64 residual in registers (group-mapped) ----
  double rr[8];
#pragma unroll
  for (int j = 0; j < 8; ++j)
    rr[j] = (double)xs[(lg * 8 + j) * 32 + sig];

  unsigned long long mk = ~0ull;           // atom-map availability bit (a*8+si)

#pragma unroll 1
  for (int it = 0; it < SPAR; ++it) {
    // ---- f32 keyscan (atom-mapped) ----
    unsigned int kb[8];
#pragma unroll
    for (int si = 0; si < 8; ++si) {
      unsigned int best = 0;
#pragma unroll
      for (int a = 0; a < 8; ++a) {
        float ac = fabsf(cor[a][si]);
        unsigned int enc = (unsigned int)(511 - (abase + a));
        unsigned int kv = (__float_as_uint(ac) & 0xFFFFFC00u) | enc;
        bool avail = (mk >> ((a << 3) + si)) & 1ull;
        kv = avail ? kv : enc;             // masked competes as value 0
        best = best > kv ? best : kv;
      }
      kb[si] = best;
    }
#pragma unroll
    for (int o = 1; o < 8; o <<= 1)
#pragma unroll
      for (int si = 0; si < 8; ++si) {
        unsigned int ok = __shfl_xor(kb[si], o);
        kb[si] = kb[si] > ok ? kb[si] : ok;
      }
    unsigned int kk = kb[0];
#pragma unroll
    for (int si = 1; si < 8; ++si) kk = ((lane & 7) == si) ? kb[si] : kk;
#pragma unroll
    for (int o = 8; o < 64; o <<= 1) {
      unsigned int ok = __shfl_xor(kk, o);
      kk = kk > ok ? kk : ok;
    }

    // ---- group-parallel fp64 winner dot (all 8 si at once) ----
    const unsigned int wkg = __shfl(kk, gsi);
    const int gig = 511 - (int)(wkg & 0x1FFu);
    double p;
    {
      const double2* dp = (const double2*)(Dd64 + ((size_t)gig << 6) + (lg << 3));
      double2 q0 = dp[0], q1 = dp[1], q2 = dp[2], q3 = dp[3];
      p = ((q0.x*rr[0] + q0.y*rr[1]) + (q1.x*rr[2] + q1.y*rr[3]))
        + ((q2.x*rr[4] + q2.y*rr[5]) + (q3.x*rr[6] + q3.y*rr[7]));
    }
    p += __shfl_xor(p, 1); p += __shfl_xor(p, 2); p += __shfl_xor(p, 4);
    unsigned long long bkey =
      ((unsigned long long)__double_as_longlong(fabs(p)) & ~0x3FFull)
      | (unsigned long long)(511 - gig);
    double bcor = p;
    int bgi = gig;

    // ---- pending extras mask (atom-mapped) ----
    unsigned long long pend = 0ull;
#pragma unroll
    for (int si = 0; si < 8; ++si) {
      unsigned int wks = __shfl(kk, si);
      int widx = 511 - (int)(wks & 0x1FFu);
      float thr = __uint_as_float(wks & 0xFFFFFC00u) * 0.999f;
#pragma unroll
      for (int a = 0; a < 8; ++a) {
        bool avail = (mk >> ((a << 3) + si)) & 1ull;
        bool inb = avail && (thr > 0.0f) && (fabsf(cor[a][si]) >= thr)
                 && ((abase + a) != widx);
        pend |= inb ? (1ull << ((a << 3) + si)) : 0ull;
      }
    }
    // ---- rare: refine extras, one per si per pass (group-parallel dots) ----
    while (__any(pend != 0ull)) {
      int myext = -1;
#pragma unroll
      for (int si = 0; si < 8; ++si) {
        unsigned long long m8 = (pend >> si) & 0x0101010101010101ull;
        unsigned long long bal = __ballot(m8 != 0ull);
        int ge = -1;
        if (bal != 0ull) {
          int src = __ffsll((long long)bal) - 1;
          unsigned long long pm = __shfl(m8, src);
          int a0 = (__ffsll((long long)pm) - 1) >> 3;
          ge = (src << 3) + a0;
        }
        if (lane == si) myext = ge;
        if (ge >= 0 && (ge >> 3) == lane)
          pend &= ~(1ull << (((ge & 7) << 3) + si));
      }
      int gie = __shfl(myext, gsi);        // group-uniform
      if (gie >= 0) {
        const double2* dp = (const double2*)(Dd64 + ((size_t)gie << 6) + (lg << 3));
        double2 q0 = dp[0], q1 = dp[1], q2 = dp[2], q3 = dp[3];
        double pe = ((q0.x*rr[0] + q0.y*rr[1]) + (q1.x*rr[2] + q1.y*rr[3]))
                  + ((q2.x*rr[4] + q2.y*rr[5]) + (q3.x*rr[6] + q3.y*rr[7]));
        pe += __shfl_xor(pe, 1); pe += __shfl_xor(pe, 2); pe += __shfl_xor(pe, 4);
        unsigned long long ke =
          ((unsigned long long)__double_as_longlong(fabs(pe)) & ~0x3FFull)
          | (unsigned long long)(511 - gie);
        if (ke > bkey) { bkey = ke; bcor = pe; bgi = gie; }
      }
    }

    // ---- finalize winner per group ----
    double alpha = bcor * rnrm[bgi];
    if (lg == 0) { s_sel[it][sig] = bgi; s_al[it][sig] = alpha; }
#pragma unroll
    for (int si = 0; si < 8; ++si) {
      int gf = __shfl(bgi, si << 3);
      if ((gf >> 3) == lane) mk &= ~(1ull << (((gf & 7) << 3) + si));
    }

    // fp64 residual update EVERY iter (z_dl comes from rr at the end)
    {
      const double2* dp = (const double2*)(Dd64 + ((size_t)bgi << 6) + (lg << 3));
      double2 q0 = dp[0], q1 = dp[1], q2 = dp[2], q3 = dp[3];
      rr[0] -= alpha*q0.x; rr[1] -= alpha*q0.y;
      rr[2] -= alpha*q1.x; rr[3] -= alpha*q1.y;
      rr[4] -= alpha*q2.x; rr[5] -= alpha*q2.y;
      rr[6] -= alpha*q3.x; rr[7] -= alpha*q3.y;
    }

    if (it != SPAR - 1) {
      // f32 Gram recursion (atom-mapped), 2 sigs per batch (register-lean)
#pragma unroll
      for (int sb = 0; sb < 8; sb += 2) {
        int   g0i = __shfl(bgi, sb << 3);
        float a0f = (float)__shfl(alpha, sb << 3);
        int   g1i = __shfl(bgi, (sb + 1) << 3);
        float a1f = (float)__shfl(alpha, (sb + 1) << 3);
        const float* gp0 = G32 + (size_t)g0i * NATOM + abase;
        const float* gp1 = G32 + (size_t)g1i * NATOM + abase;
        float4 u0 = *(const float4*)gp0;
        float4 u1 = *(const float4*)(gp0 + 4);
        float4 v0 = *(const float4*)gp1;
        float4 v1 = *(const float4*)(gp1 + 4);
        cor[0][sb] -= a0f*u0.x; cor[1][sb] -= a0f*u0.y;
        cor[2][sb] -= a0f*u0.z; cor[3][sb] -= a0f*u0.w;
        cor[4][sb] -= a0f*u1.x; cor[5][sb] -= a0f*u1.y;
        cor[6][sb] -= a0f*u1.z; cor[7][sb] -= a0f*u1.w;
        cor[0][sb+1] -= a1f*v0.x; cor[1][sb+1] -= a1f*v0.y;
        cor[2][sb+1] -= a1f*v0.z; cor[3][sb+1] -= a1f*v0.w;
        cor[4][sb+1] -= a1f*v1.x; cor[5][sb+1] -= a1f*v1.y;
        cor[6][sb+1] -= a1f*v1.z; cor[7][sb+1] -= a1f*v1.w;
      }
    }
  }
  __syncthreads();                         // publish s_sel/s_al; xs reads done

  // ---- epilogue A: zv = f32(x - rr) into xs (own slots) + loss ----
  {
    double s2 = 0.0;
    const int d0 = lg << 3;
#pragma unroll
    for (int j = 0; j < 8; ++j) {
      int idx = (d0 + j) * 32 + sig;
      double x = (double)xs[idx];
      float zv = (float)(x - rr[j]);
      xs[idx] = zv;                        // single-owner slot, no race
      double diff = (double)zv - x;
      s2 += diff * diff;
    }
#pragma unroll
    for (int o = 1; o < 64; o <<= 1) s2 += __shfl_xor(s2, o);
    if (lane == 0) s_red[w] = s2;
  }

  // ---- epilogue B part 1: coeff zero-fill (coalesced 128B runs) ----
  {
    const float4 z4 = make_float4(0.f, 0.f, 0.f, 0.f);
#pragma unroll
    for (int p2 = 0; p2 < 16; ++p2) {
      int idx = tid + (p2 << 8);           // 0..4095 = atom*8 + quad
      int a = idx >> 3, q = idx & 7;
      *(float4*)(coeff + (size_t)a * NSIG + ((size_t)l << 5) + (q << 2)) = z4;
    }
  }
  __syncthreads();                         // zv in xs ready; zeros ordered

  // ---- epilogue C: coalesced zv write-back into xw slice (in-place safe) ----
  {
    float* dst = xw + (size_t)l * 2048 + tid * 8;
    float4 v0 = *(const float4*)&xs[tid * 8];
    float4 v1 = *(const float4*)&xs[tid * 8 + 4];
    *(float4*)dst       = v0;
    *(float4*)(dst + 4) = v1;
  }
  if (tid == 0) partial[bid] = (s_red[0] + s_red[1]) + (s_red[2] + s_red[3]);
  if (tid < 32) {
#pragma unroll
    for (int tt = 0; tt < SPAR; ++tt) {
      int gi = s_sel[tt][tid];
      coeff[(size_t)gi * NSIG + ((size_t)l << 5) + tid] = (float)s_al[tt][tid];
    }
  }
}

// ---- finalize loss ---------------------------------------------------------
__global__ __launch_bounds__(64) void finalize_kernel(const double* __restrict__ partial,
                                                      float* __restrict__ loss_out) {
  double s = 0.0;
  for (int i = threadIdx.x; i < 1024; i += 64) s += partial[i];
#pragma unroll
  for (int o = 32; o > 0; o >>= 1) s += __shfl_down(s, o);
  if (threadIdx.x == 0) loss_out[0] = (float)(1.25 * s / 2097152.0);
}

extern "C" void kernel_launch(void* const* d_in, const int* in_sizes, int n_in,
                              void* d_out, int out_size, void* d_ws, size_t ws_size,
                              hipStream_t stream) {
  const float* z_e = (const float*)d_in[0];
  const float* D   = (const float*)d_in[1];

  float* out      = (float*)d_out;
  float* z_dl     = out;                       // 2097152 elems
  float* loss_out = out + 2097152;             // 1 elem
  float* coeff    = out + 2097153;             // 512*32768 elems

  char*   ws      = (char*)d_ws;
  double* partial = (double*)ws;                               // 8 KiB (1024)
  float*  Dt32    = (float*) (ws + 8192);                      // 128 KiB
  double* Dd64    = (double*)(ws + 8192 + 131072);             // 256 KiB
  double* rnrm    = (double*)(ws + 8192 + 131072 + 262144);    // 4 KiB
  float*  G32     = (float*) (ws + 8192 + 131072 + 262144 + 4096);           // 1 MiB
  float*  xw      = (float*) (ws + 8192 + 131072 + 262144 + 4096 + 1048576); // 8 MiB

  prep_kernel<<<1, 512, 0, stream>>>(D, Dt32, Dd64, rnrm);
  gram_kernel<<<NATOM, NATOM, 0, stream>>>(Dt32, G32);
  repack_kernel<<<2048, 256, 0, stream>>>(z_e, xw);
  omp12_kernel<<<1024, 256, 0, stream>>>(xw, Dt32, Dd64, rnrm, G32, coeff, partial);
  unpack_kernel<<<2048, 256, 0, stream>>>(xw, z_dl);
  finalize_kernel<<<1, 64, 0, stream>>>(partial, loss_out);
}

// Round 17
// 126.141 us; speedup vs baseline: 2.5941x; 1.0712x over previous
//
#include <hip/hip_runtime.h>
#include <stdint.h>

#define NSIG   32768
#define NATOM  512
#define MDIM   64
#define SPAR   5
#define EPS    1e-10

// ---- prep: fp64 norms; Dt32 [dim][atom] f32; Dd64 [atom][dim] f64;
// ----       rnrm = 1/(||d||^2+eps) f64.  8 blocks x 64 threads: coalesced
// ----       row reads, per-atom math order identical to prior rounds.
__global__ __launch_bounds__(64) void prep_kernel(const float* __restrict__ D,
                                                  float*  __restrict__ Dt32,
                                                  double* __restrict__ Dd64,
                                                  double* __restrict__ rnrm) {
  int n = blockIdx.x * 64 + threadIdx.x;   // atom 0..511
  double ss = 0.0;
#pragma unroll 8
  for (int c = 0; c < MDIM; ++c) {
    double v = (double)D[c * NATOM + n];
    ss += v * v;
  }
  double norm = sqrt(ss);
  if (norm < 1e-10) norm = 1e-10;
  double s2 = 0.0;
#pragma unroll 8
  for (int c = 0; c < MDIM; ++c) {
    double v = (double)D[c * NATOM + n] / norm;
    Dd64[((size_t)n << 6) + c]  = v;
    Dt32[(size_t)c * NATOM + n] = (float)v;
    s2 += v * v;
  }
  rnrm[n] = 1.0 / (s2 + EPS);
}

// ---- fused: repack (bid<2048) | Gram f32 (bid>=2048) ------------------------
// repack: xw[l][c*32+b] = z_e[b][c][l] via LDS transpose (both sides coalesced)
// gram:   G32[i][j] = <Dn_i, Dn_j> f32 (steers the f32 corr recursion only)
__global__ __launch_bounds__(256) void gram_repack_kernel(const float* __restrict__ z_e,
                                                          float* __restrict__ xw,
                                                          const float* __restrict__ Dt32,
                                                          float* __restrict__ G32) {
  __shared__ float t[32][33];
  const int bid = blockIdx.x;
  if (bid < 2048) {
    const int c  = bid & 63;
    const int l0 = (bid >> 6) << 5;
    const int tr = threadIdx.x >> 5;       // 0..7
    const int tc = threadIdx.x & 31;
#pragma unroll
    for (int p = 0; p < 4; ++p) {
      int b = tr + p * 8;
      t[b][tc] = z_e[(size_t)b * 65536 + (size_t)c * 1024 + l0 + tc];
    }
    __syncthreads();
#pragma unroll
    for (int p = 0; p < 4; ++p) {
      int lr = tr + p * 8;
      xw[(size_t)(l0 + lr) * 2048 + c * 32 + tc] = t[tc][lr];
    }
  } else {
    const int i = bid - 2048;              // gram row
#pragma unroll
    for (int half = 0; half < 2; ++half) {
      int j = threadIdx.x + half * 256;
      float s = 0.f;
#pragma unroll 8
      for (int c = 0; c < MDIM; ++c)
        s += Dt32[(size_t)c * NATOM + i] * Dt32[(size_t)c * NATOM + j];
      G32[(size_t)i * NATOM + j] = s;
    }
  }
}

// ---- main OMP kernel: f32 GEMM/scan/Gram + group-parallel fp64 refinement ---
// block = 256 = 4 waves, 32 sigs/block (token l). Wave w owns sigs [8w,8w+8).
// Atom-map: lane owns atoms [lane*8,lane*8+8) (cor[8][8] f32).
// Group-map: lane (gsi=lane>>3, lg=lane&7) holds fp64 residual dims
// [8lg,8lg+8) of signal w*8+gsi in registers (rr[8]).
__global__ __launch_bounds__(256) void omp12_kernel(float* __restrict__ xw,
                                                    const float* __restrict__ Dt32,
                                                    const double* __restrict__ Dd64,
                                                    const double* __restrict__ rnrm,
                                                    const float* __restrict__ G32,
                                                    float* __restrict__ coeff,
                                                    double* __restrict__ partial) {
  __shared__ float  xs[2048];              // 8 KiB x f32 slice (later: zv values)
  __shared__ double s_al[SPAR][32];
  __shared__ int    s_sel[SPAR][32];
  __shared__ double s_red[4];

  const int tid  = threadIdx.x;
  const int w    = __builtin_amdgcn_readfirstlane(tid >> 6);
  const int lane = tid & 63;
  const int abase = lane << 3;             // atom-map
  const int gsi  = lane >> 3;              // group-map: signal within wave
  const int lg   = lane & 7;               // group-map: dim-oct
  const int sig  = (w << 3) + gsi;
  const int bid  = blockIdx.x;
  const int l    = ((bid & 7) << 7) | (bid >> 3);   // XCD swizzle (bijective)

  // ---- stage x slice into LDS (coalesced, stride-16B = bank-conflict-free) --
  {
    const float* src = xw + (size_t)l * 2048;
#pragma unroll
    for (int p = 0; p < 2; ++p)
      *(float4*)&xs[tid * 4 + p * 1024] = *(const float4*)(src + tid * 4 + p * 1024);
  }
  __syncthreads();

  float cor[8][8];                         // [atom][sig] f32
#pragma unroll
  for (int a = 0; a < 8; ++a)
#pragma unroll
    for (int si = 0; si < 8; ++si) cor[a][si] = 0.0f;

  // ---- phase 1: f32 register GEMM, 2-deep D prefetch, x broadcast from LDS --
  {
    const float* dbase = Dt32 + abase;
    const int xo = w << 3;
    float4 dA0 = *(const float4*)dbase;
    float4 dB0 = *(const float4*)(dbase + 4);
    float4 dA1 = *(const float4*)(dbase + NATOM);
    float4 dB1 = *(const float4*)(dbase + NATOM + 4);
    for (int k = 0; k < MDIM; k += 2) {
      float4 xA0 = *(const float4*)&xs[k * 32 + xo];
      float4 xB0 = *(const float4*)&xs[k * 32 + xo + 4];
      float4 xA1 = *(const float4*)&xs[(k + 1) * 32 + xo];
      float4 xB1 = *(const float4*)&xs[(k + 1) * 32 + xo + 4];
      float dv0[8] = {dA0.x, dA0.y, dA0.z, dA0.w, dB0.x, dB0.y, dB0.z, dB0.w};
      float xv0[8] = {xA0.x, xA0.y, xA0.z, xA0.w, xB0.x, xB0.y, xB0.z, xB0.w};
      float dv1[8] = {dA1.x, dA1.y, dA1.z, dA1.w, dB1.x, dB1.y, dB1.z, dB1.w};
      float xv1[8] = {xA1.x, xA1.y, xA1.z, xA1.w, xB1.x, xB1.y, xB1.z, xB1.w};
      if (k + 2 < MDIM) {
        const float* dn = dbase + (size_t)(k + 2) * NATOM;
        dA0 = *(const float4*)dn; dB0 = *(const float4*)(dn + 4);
        const float* dm = dbase + (size_t)(k + 3) * NATOM;
        dA1 = *(const float4*)dm; dB1 = *(const float4*)(dm + 4);
      }
#pragma unroll
      for (int a = 0; a < 8; ++a)
#pragma unroll
        for (int si = 0; si < 8; ++si)
          cor[a][si] += dv0[a] * xv0[si];
#pragma unroll
      for (int a = 0; a < 8; ++a)
#pragma unroll
        for (int si = 0; si < 8; ++si)
          cor[a][si] += dv1[a] * xv1[si];
    }
  }

  // ---- fp64 residual in registers (group-mapped) ----
  double rr[8];
#pragma unroll
  for (int j = 0; j < 8; ++j)
    rr[j] = (double)xs[(lg * 8 + j) * 32 + sig];

  unsigned long long mk = ~0ull;           // atom-map availability bit (a*8+si)

#pragma unroll 1
  for (int it = 0; it < SPAR; ++it) {
    // ---- f32 keyscan (atom-mapped) ----
    unsigned int kb[8];
#pragma unroll
    for (int si = 0; si < 8; ++si) {
      unsigned int best = 0;
#pragma unroll
      for (int a = 0; a < 8; ++a) {
        float ac = fabsf(cor[a][si]);
        unsigned int enc = (unsigned int)(511 - (abase + a));
        unsigned int kv = (__float_as_uint(ac) & 0xFFFFFC00u) | enc;
        bool avail = (mk >> ((a << 3) + si)) & 1ull;
        kv = avail ? kv : enc;             // masked competes as value 0
        best = best > kv ? best : kv;
      }
      kb[si] = best;
    }
#pragma unroll
    for (int o = 1; o < 8; o <<= 1)
#pragma unroll
      for (int si = 0; si < 8; ++si) {
        unsigned int ok = __shfl_xor(kb[si], o);
        kb[si] = kb[si] > ok ? kb[si] : ok;
      }
    unsigned int kk = kb[0];
#pragma unroll
    for (int si = 1; si < 8; ++si) kk = ((lane & 7) == si) ? kb[si] : kk;
#pragma unroll
    for (int o = 8; o < 64; o <<= 1) {
      unsigned int ok = __shfl_xor(kk, o);
      kk = kk > ok ? kk : ok;
    }

    // ---- group-parallel fp64 winner dot (all 8 si at once) ----
    const unsigned int wkg = __shfl(kk, gsi);
    const int gig = 511 - (int)(wkg & 0x1FFu);
    double p;
    {
      const double2* dp = (const double2*)(Dd64 + ((size_t)gig << 6) + (lg << 3));
      double2 q0 = dp[0], q1 = dp[1], q2 = dp[2], q3 = dp[3];
      p = ((q0.x*rr[0] + q0.y*rr[1]) + (q1.x*rr[2] + q1.y*rr[3]))
        + ((q2.x*rr[4] + q2.y*rr[5]) + (q3.x*rr[6] + q3.y*rr[7]));
    }
    p += __shfl_xor(p, 1); p += __shfl_xor(p, 2); p += __shfl_xor(p, 4);
    unsigned long long bkey =
      ((unsigned long long)__double_as_longlong(fabs(p)) & ~0x3FFull)
      | (unsigned long long)(511 - gig);
    double bcor = p;
    int bgi = gig;

    // ---- pending extras mask (atom-mapped) ----
    unsigned long long pend = 0ull;
#pragma unroll
    for (int si = 0; si < 8; ++si) {
      unsigned int wks = __shfl(kk, si);
      int widx = 511 - (int)(wks & 0x1FFu);
      float thr = __uint_as_float(wks & 0xFFFFFC00u) * 0.999f;
#pragma unroll
      for (int a = 0; a < 8; ++a) {
        bool avail = (mk >> ((a << 3) + si)) & 1ull;
        bool inb = avail && (thr > 0.0f) && (fabsf(cor[a][si]) >= thr)
                 && ((abase + a) != widx);
        pend |= inb ? (1ull << ((a << 3) + si)) : 0ull;
      }
    }
    // ---- rare: refine extras, one per si per pass (group-parallel dots) ----
    while (__any(pend != 0ull)) {
      int myext = -1;
#pragma unroll
      for (int si = 0; si < 8; ++si) {
        unsigned long long m8 = (pend >> si) & 0x0101010101010101ull;
        unsigned long long bal = __ballot(m8 != 0ull);
        int ge = -1;
        if (bal != 0ull) {
          int src = __ffsll((long long)bal) - 1;
          unsigned long long pm = __shfl(m8, src);
          int a0 = (__ffsll((long long)pm) - 1) >> 3;
          ge = (src << 3) + a0;
        }
        if (lane == si) myext = ge;
        if (ge >= 0 && (ge >> 3) == lane)
          pend &= ~(1ull << (((ge & 7) << 3) + si));
      }
      int gie = __shfl(myext, gsi);        // group-uniform
      if (gie >= 0) {
        const double2* dp = (const double2*)(Dd64 + ((size_t)gie << 6) + (lg << 3));
        double2 q0 = dp[0], q1 = dp[1], q2 = dp[2], q3 = dp[3];
        double pe = ((q0.x*rr[0] + q0.y*rr[1]) + (q1.x*rr[2] + q1.y*rr[3]))
                  + ((q2.x*rr[4] + q2.y*rr[5]) + (q3.x*rr[6] + q3.y*rr[7]));
        pe += __shfl_xor(pe, 1); pe += __shfl_xor(pe, 2); pe += __shfl_xor(pe, 4);
        unsigned long long ke =
          ((unsigned long long)__double_as_longlong(fabs(pe)) & ~0x3FFull)
          | (unsigned long long)(511 - gie);
        if (ke > bkey) { bkey = ke; bcor = pe; bgi = gie; }
      }
    }

    // ---- finalize winner per group ----
    double alpha = bcor * rnrm[bgi];
    if (lg == 0) { s_sel[it][sig] = bgi; s_al[it][sig] = alpha; }
#pragma unroll
    for (int si = 0; si < 8; ++si) {
      int gf = __shfl(bgi, si << 3);
      if ((gf >> 3) == lane) mk &= ~(1ull << (((gf & 7) << 3) + si));
    }

    // fp64 residual update EVERY iter (z_dl comes from rr at the end)
    {
      const double2* dp = (const double2*)(Dd64 + ((size_t)bgi << 6) + (lg << 3));
      double2 q0 = dp[0], q1 = dp[1], q2 = dp[2], q3 = dp[3];
      rr[0] -= alpha*q0.x; rr[1] -= alpha*q0.y;
      rr[2] -= alpha*q1.x; rr[3] -= alpha*q1.y;
      rr[4] -= alpha*q2.x; rr[5] -= alpha*q2.y;
      rr[6] -= alpha*q3.x; rr[7] -= alpha*q3.y;
    }

    if (it != SPAR - 1) {
      // f32 Gram recursion (atom-mapped), 2 sigs per batch (register-lean)
#pragma unroll
      for (int sb = 0; sb < 8; sb += 2) {
        int   g0i = __shfl(bgi, sb << 3);
        float a0f = (float)__shfl(alpha, sb << 3);
        int   g1i = __shfl(bgi, (sb + 1) << 3);
        float a1f = (float)__shfl(alpha, (sb + 1) << 3);
        const float* gp0 = G32 + (size_t)g0i * NATOM + abase;
        const float* gp1 = G32 + (size_t)g1i * NATOM + abase;
        float4 u0 = *(const float4*)gp0;
        float4 u1 = *(const float4*)(gp0 + 4);
        float4 v0 = *(const float4*)gp1;
        float4 v1 = *(const float4*)(gp1 + 4);
        cor[0][sb] -= a0f*u0.x; cor[1][sb] -= a0f*u0.y;
        cor[2][sb] -= a0f*u0.z; cor[3][sb] -= a0f*u0.w;
        cor[4][sb] -= a0f*u1.x; cor[5][sb] -= a0f*u1.y;
        cor[6][sb] -= a0f*u1.z; cor[7][sb] -= a0f*u1.w;
        cor[0][sb+1] -= a1f*v0.x; cor[1][sb+1] -= a1f*v0.y;
        cor[2][sb+1] -= a1f*v0.z; cor[3][sb+1] -= a1f*v0.w;
        cor[4][sb+1] -= a1f*v1.x; cor[5][sb+1] -= a1f*v1.y;
        cor[6][sb+1] -= a1f*v1.z; cor[7][sb+1] -= a1f*v1.w;
      }
    }
  }
  __syncthreads();                         // publish s_sel/s_al; xs reads done

  // ---- epilogue A: zv = f32(x - rr) into xs (own slots) + loss ----
  {
    double s2 = 0.0;
    const int d0 = lg << 3;
#pragma unroll
    for (int j = 0; j < 8; ++j) {
      int idx = (d0 + j) * 32 + sig;
      double x = (double)xs[idx];
      float zv = (float)(x - rr[j]);
      xs[idx] = zv;                        // single-owner slot, no race
      double diff = (double)zv - x;
      s2 += diff * diff;
    }
#pragma unroll
    for (int o = 1; o < 64; o <<= 1) s2 += __shfl_xor(s2, o);
    if (lane == 0) s_red[w] = s2;
  }

  // ---- epilogue B part 1: coeff zero-fill (coalesced 128B runs) ----
  {
    const float4 z4 = make_float4(0.f, 0.f, 0.f, 0.f);
#pragma unroll
    for (int p2 = 0; p2 < 16; ++p2) {
      int idx = tid + (p2 << 8);           // 0..4095 = atom*8 + quad
      int a = idx >> 3, q = idx & 7;
      *(float4*)(coeff + (size_t)a * NSIG + ((size_t)l << 5) + (q << 2)) = z4;
    }
  }
  __syncthreads();                         // zv in xs ready; zeros ordered

  // ---- epilogue C: coalesced zv write-back (stride-16B, conflict-free) ----
  {
    float* dst = xw + (size_t)l * 2048;
#pragma unroll
    for (int p = 0; p < 2; ++p)
      *(float4*)(dst + tid * 4 + p * 1024) = *(const float4*)&xs[tid * 4 + p * 1024];
  }
  if (tid == 0) partial[bid] = (s_red[0] + s_red[1]) + (s_red[2] + s_red[3]);
  if (tid < 32) {
#pragma unroll
    for (int tt = 0; tt < SPAR; ++tt) {
      int gi = s_sel[tt][tid];
      coeff[(size_t)gi * NSIG + ((size_t)l << 5) + tid] = (float)s_al[tt][tid];
    }
  }
}

// ---- fused: unpack (bid<2048) | finalize loss (bid==2048) -------------------
__global__ __launch_bounds__(256) void unpack_fin_kernel(const float* __restrict__ xw,
                                                         float* __restrict__ z_dl,
                                                         const double* __restrict__ partial,
                                                         float* __restrict__ loss_out) {
  __shared__ float t[32][33];
  const int bid = blockIdx.x;
  if (bid < 2048) {
    const int c  = bid & 63;
    const int l0 = (bid >> 6) << 5;
    const int tr = threadIdx.x >> 5;       // 0..7
    const int tc = threadIdx.x & 31;
#pragma unroll
    for (int p = 0; p < 4; ++p) {
      int lr = tr + p * 8;                 // read coalesced in b (=tc)
      t[lr][tc] = xw[(size_t)(l0 + lr) * 2048 + c * 32 + tc];
    }
    __syncthreads();
#pragma unroll
    for (int p = 0; p < 4; ++p) {
      int b = tr + p * 8;                  // write coalesced in l (=tc)
      z_dl[(size_t)b * 65536 + (size_t)c * 1024 + l0 + tc] = t[tc][b];
    }
  } else if (threadIdx.x < 64) {
    double s = 0.0;
    for (int i = threadIdx.x; i < 1024; i += 64) s += partial[i];
#pragma unroll
    for (int o = 32; o > 0; o >>= 1) s += __shfl_down(s, o);
    if (threadIdx.x == 0) loss_out[0] = (float)(1.25 * s / 2097152.0);
  }
}

extern "C" void kernel_launch(void* const* d_in, const int* in_sizes, int n_in,
                              void* d_out, int out_size, void* d_ws, size_t ws_size,
                              hipStream_t stream) {
  const float* z_e = (const float*)d_in[0];
  const float* D   = (const float*)d_in[1];

  float* out      = (float*)d_out;
  float* z_dl     = out;                       // 2097152 elems
  float* loss_out = out + 2097152;             // 1 elem
  float* coeff    = out + 2097153;             // 512*32768 elems

  char*   ws      = (char*)d_ws;
  double* partial = (double*)ws;                               // 8 KiB (1024)
  float*  Dt32    = (float*) (ws + 8192);                      // 128 KiB
  double* Dd64    = (double*)(ws + 8192 + 131072);             // 256 KiB
  double* rnrm    = (double*)(ws + 8192 + 131072 + 262144);    // 4 KiB
  float*  G32     = (float*) (ws + 8192 + 131072 + 262144 + 4096);           // 1 MiB
  float*  xw      = (float*) (ws + 8192 + 131072 + 262144 + 4096 + 1048576); // 8 MiB

  prep_kernel<<<8, 64, 0, stream>>>(D, Dt32, Dd64, rnrm);
  gram_repack_kernel<<<2560, 256, 0, stream>>>(z_e, xw, Dt32, G32);
  omp12_kernel<<<1024, 256, 0, stream>>>(xw, Dt32, Dd64, rnrm, G32, coeff, partial);
  unpack_fin_kernel<<<2049, 256, 0, stream>>>(xw, z_dl, partial, loss_out);
}

// Round 18
// 125.504 us; speedup vs baseline: 2.6073x; 1.0051x over previous
//
#include <hip/hip_runtime.h>
#include <stdint.h>

#define NSIG   32768
#define NATOM  512
#define MDIM   64
#define SPAR   5
#define EPS    1e-10

// xs bank swizzle: XOR float-index bank bits with row-octet (i>>8 = d>>3).
// Involution; wave-uniform & 16B-aligned for all float4 paths; spreads the
// stride-32 column accesses from 8-way conflict to 2-way (free).
__device__ __forceinline__ int SW(int i) { return i ^ (((i >> 8) & 7) << 2); }

// ---- prep: fp64 norms; Dt32 [dim][atom] f32; Dd64 [atom][dim] f64;
// ----       rnrm = 1/(||d||^2+eps) f64
__global__ __launch_bounds__(64) void prep_kernel(const float* __restrict__ D,
                                                  float*  __restrict__ Dt32,
                                                  double* __restrict__ Dd64,
                                                  double* __restrict__ rnrm) {
  int n = blockIdx.x * 64 + threadIdx.x;   // atom 0..511
  double ss = 0.0;
#pragma unroll 8
  for (int c = 0; c < MDIM; ++c) {
    double v = (double)D[c * NATOM + n];
    ss += v * v;
  }
  double norm = sqrt(ss);
  if (norm < 1e-10) norm = 1e-10;
  double s2 = 0.0;
#pragma unroll 8
  for (int c = 0; c < MDIM; ++c) {
    double v = (double)D[c * NATOM + n] / norm;
    Dd64[((size_t)n << 6) + c]  = v;
    Dt32[(size_t)c * NATOM + n] = (float)v;
    s2 += v * v;
  }
  rnrm[n] = 1.0 / (s2 + EPS);
}

// ---- fused: repack (bid<2048) | Gram f32 (bid>=2048) ------------------------
__global__ __launch_bounds__(256) void gram_repack_kernel(const float* __restrict__ z_e,
                                                          float* __restrict__ xw,
                                                          const float* __restrict__ Dt32,
                                                          float* __restrict__ G32) {
  __shared__ float t[32][33];
  const int bid = blockIdx.x;
  if (bid < 2048) {
    const int c  = bid & 63;
    const int l0 = (bid >> 6) << 5;
    const int tr = threadIdx.x >> 5;       // 0..7
    const int tc = threadIdx.x & 31;
#pragma unroll
    for (int p = 0; p < 4; ++p) {
      int b = tr + p * 8;
      t[b][tc] = z_e[(size_t)b * 65536 + (size_t)c * 1024 + l0 + tc];
    }
    __syncthreads();
#pragma unroll
    for (int p = 0; p < 4; ++p) {
      int lr = tr + p * 8;
      xw[(size_t)(l0 + lr) * 2048 + c * 32 + tc] = t[tc][lr];
    }
  } else {
    const int i = bid - 2048;              // gram row
#pragma unroll
    for (int half = 0; half < 2; ++half) {
      int j = threadIdx.x + half * 256;
      float s = 0.f;
#pragma unroll 8
      for (int c = 0; c < MDIM; ++c)
        s += Dt32[(size_t)c * NATOM + i] * Dt32[(size_t)c * NATOM + j];
      G32[(size_t)i * NATOM + j] = s;
    }
  }
}

// ---- main OMP kernel: f32 GEMM/scan/Gram + group-parallel fp64 refinement ---
__global__ __launch_bounds__(256) void omp12_kernel(float* __restrict__ xw,
                                                    const float* __restrict__ Dt32,
                                                    const double* __restrict__ Dd64,
                                                    const double* __restrict__ rnrm,
                                                    const float* __restrict__ G32,
                                                    float* __restrict__ coeff,
                                                    double* __restrict__ partial) {
  __shared__ float  xs[2048];              // 8 KiB x f32 slice (bank-swizzled)
  __shared__ double s_al[SPAR][32];
  __shared__ int    s_sel[SPAR][32];
  __shared__ double s_red[4];

  const int tid  = threadIdx.x;
  const int w    = __builtin_amdgcn_readfirstlane(tid >> 6);
  const int lane = tid & 63;
  const int abase = lane << 3;             // atom-map
  const int gsi  = lane >> 3;              // group-map: signal within wave
  const int lg   = lane & 7;               // group-map: dim-oct
  const int sig  = (w << 3) + gsi;
  const int bid  = blockIdx.x;
  const int l    = ((bid & 7) << 7) | (bid >> 3);   // XCD swizzle (bijective)

  // ---- stage x slice into LDS (coalesced; swizzled dest) ----
  {
    const float* src = xw + (size_t)l * 2048;
#pragma unroll
    for (int p = 0; p < 2; ++p)
      *(float4*)&xs[SW(tid * 4 + p * 1024)] = *(const float4*)(src + tid * 4 + p * 1024);
  }
  __syncthreads();

  float cor[8][8];                         // [atom][sig] f32
#pragma unroll
  for (int a = 0; a < 8; ++a)
#pragma unroll
    for (int si = 0; si < 8; ++si) cor[a][si] = 0.0f;

  // ---- phase 1: f32 register GEMM, 2-deep D prefetch, x broadcast from LDS --
  {
    const float* dbase = Dt32 + abase;
    const int xo = w << 3;
    float4 dA0 = *(const float4*)dbase;
    float4 dB0 = *(const float4*)(dbase + 4);
    float4 dA1 = *(const float4*)(dbase + NATOM);
    float4 dB1 = *(const float4*)(dbase + NATOM + 4);
    for (int k = 0; k < MDIM; k += 2) {
      float4 xA0 = *(const float4*)&xs[SW(k * 32 + xo)];
      float4 xB0 = *(const float4*)&xs[SW(k * 32 + xo + 4)];
      float4 xA1 = *(const float4*)&xs[SW((k + 1) * 32 + xo)];
      float4 xB1 = *(const float4*)&xs[SW((k + 1) * 32 + xo + 4)];
      float dv0[8] = {dA0.x, dA0.y, dA0.z, dA0.w, dB0.x, dB0.y, dB0.z, dB0.w};
      float xv0[8] = {xA0.x, xA0.y, xA0.z, xA0.w, xB0.x, xB0.y, xB0.z, xB0.w};
      float dv1[8] = {dA1.x, dA1.y, dA1.z, dA1.w, dB1.x, dB1.y, dB1.z, dB1.w};
      float xv1[8] = {xA1.x, xA1.y, xA1.z, xA1.w, xB1.x, xB1.y, xB1.z, xB1.w};
      if (k + 2 < MDIM) {
        const float* dn = dbase + (size_t)(k + 2) * NATOM;
        dA0 = *(const float4*)dn; dB0 = *(const float4*)(dn + 4);
        const float* dm = dbase + (size_t)(k + 3) * NATOM;
        dA1 = *(const float4*)dm; dB1 = *(const float4*)(dm + 4);
      }
#pragma unroll
      for (int a = 0; a < 8; ++a)
#pragma unroll
        for (int si = 0; si < 8; ++si)
          cor[a][si] += dv0[a] * xv0[si];
#pragma unroll
      for (int a = 0; a < 8; ++a)
#pragma unroll
        for (int si = 0; si < 8; ++si)
          cor[a][si] += dv1[a] * xv1[si];
    }
  }

  // ---- fp64 residual in registers (group-mapped; swizzled reads) ----
  double rr[8];
#pragma unroll
  for (int j = 0; j < 8; ++j)
    rr[j] = (double)xs[SW((lg * 8 + j) * 32 + sig)];

  unsigned long long mk = ~0ull;           // atom-map availability bit (a*8+si)

#pragma unroll 1
  for (int it = 0; it < SPAR; ++it) {
    // ---- f32 keyscan (atom-mapped) ----
    unsigned int kb[8];
#pragma unroll
    for (int si = 0; si < 8; ++si) {
      unsigned int best = 0;
#pragma unroll
      for (int a = 0; a < 8; ++a) {
        float ac = fabsf(cor[a][si]);
        unsigned int enc = (unsigned int)(511 - (abase + a));
        unsigned int kv = (__float_as_uint(ac) & 0xFFFFFC00u) | enc;
        bool avail = (mk >> ((a << 3) + si)) & 1ull;
        kv = avail ? kv : enc;             // masked competes as value 0
        best = best > kv ? best : kv;
      }
      kb[si] = best;
    }
#pragma unroll
    for (int o = 1; o < 8; o <<= 1)
#pragma unroll
      for (int si = 0; si < 8; ++si) {
        unsigned int ok = __shfl_xor(kb[si], o);
        kb[si] = kb[si] > ok ? kb[si] : ok;
      }
    unsigned int kk = kb[0];
#pragma unroll
    for (int si = 1; si < 8; ++si) kk = ((lane & 7) == si) ? kb[si] : kk;
#pragma unroll
    for (int o = 8; o < 64; o <<= 1) {
      unsigned int ok = __shfl_xor(kk, o);
      kk = kk > ok ? kk : ok;
    }

    // ---- group-parallel fp64 winner dot (all 8 si at once) ----
    const unsigned int wkg = __shfl(kk, gsi);
    const int gig = 511 - (int)(wkg & 0x1FFu);
    double p;
    {
      const double2* dp = (const double2*)(Dd64 + ((size_t)gig << 6) + (lg << 3));
      double2 q0 = dp[0], q1 = dp[1], q2 = dp[2], q3 = dp[3];
      p = ((q0.x*rr[0] + q0.y*rr[1]) + (q1.x*rr[2] + q1.y*rr[3]))
        + ((q2.x*rr[4] + q2.y*rr[5]) + (q3.x*rr[6] + q3.y*rr[7]));
    }
    p += __shfl_xor(p, 1); p += __shfl_xor(p, 2); p += __shfl_xor(p, 4);
    unsigned long long bkey =
      ((unsigned long long)__double_as_longlong(fabs(p)) & ~0x3FFull)
      | (unsigned long long)(511 - gig);
    double bcor = p;
    int bgi = gig;

    // ---- pending extras mask (atom-mapped) ----
    unsigned long long pend = 0ull;
#pragma unroll
    for (int si = 0; si < 8; ++si) {
      unsigned int wks = __shfl(kk, si);
      int widx = 511 - (int)(wks & 0x1FFu);
      float thr = __uint_as_float(wks & 0xFFFFFC00u) * 0.999f;
#pragma unroll
      for (int a = 0; a < 8; ++a) {
        bool avail = (mk >> ((a << 3) + si)) & 1ull;
        bool inb = avail && (thr > 0.0f) && (fabsf(cor[a][si]) >= thr)
                 && ((abase + a) != widx);
        pend |= inb ? (1ull << ((a << 3) + si)) : 0ull;
      }
    }
    // ---- rare: refine extras, one per si per pass (group-parallel dots) ----
    while (__any(pend != 0ull)) {
      int myext = -1;
#pragma unroll
      for (int si = 0; si < 8; ++si) {
        unsigned long long m8 = (pend >> si) & 0x0101010101010101ull;
        unsigned long long bal = __ballot(m8 != 0ull);
        int ge = -1;
        if (bal != 0ull) {
          int src = __ffsll((long long)bal) - 1;
          unsigned long long pm = __shfl(m8, src);
          int a0 = (__ffsll((long long)pm) - 1) >> 3;
          ge = (src << 3) + a0;
        }
        if (lane == si) myext = ge;
        if (ge >= 0 && (ge >> 3) == lane)
          pend &= ~(1ull << (((ge & 7) << 3) + si));
      }
      int gie = __shfl(myext, gsi);        // group-uniform
      if (gie >= 0) {
        const double2* dp = (const double2*)(Dd64 + ((size_t)gie << 6) + (lg << 3));
        double2 q0 = dp[0], q1 = dp[1], q2 = dp[2], q3 = dp[3];
        double pe = ((q0.x*rr[0] + q0.y*rr[1]) + (q1.x*rr[2] + q1.y*rr[3]))
                  + ((q2.x*rr[4] + q2.y*rr[5]) + (q3.x*rr[6] + q3.y*rr[7]));
        pe += __shfl_xor(pe, 1); pe += __shfl_xor(pe, 2); pe += __shfl_xor(pe, 4);
        unsigned long long ke =
          ((unsigned long long)__double_as_longlong(fabs(pe)) & ~0x3FFull)
          | (unsigned long long)(511 - gie);
        if (ke > bkey) { bkey = ke; bcor = pe; bgi = gie; }
      }
    }

    // ---- finalize winner per group ----
    double alpha = bcor * rnrm[bgi];
    if (lg == 0) { s_sel[it][sig] = bgi; s_al[it][sig] = alpha; }
#pragma unroll
    for (int si = 0; si < 8; ++si) {
      int gf = __shfl(bgi, si << 3);
      if ((gf >> 3) == lane) mk &= ~(1ull << (((gf & 7) << 3) + si));
    }

    // fp64 residual update EVERY iter (z_dl comes from rr at the end)
    {
      const double2* dp = (const double2*)(Dd64 + ((size_t)bgi << 6) + (lg << 3));
      double2 q0 = dp[0], q1 = dp[1], q2 = dp[2], q3 = dp[3];
      rr[0] -= alpha*q0.x; rr[1] -= alpha*q0.y;
      rr[2] -= alpha*q1.x; rr[3] -= alpha*q1.y;
      rr[4] -= alpha*q2.x; rr[5] -= alpha*q2.y;
      rr[6] -= alpha*q3.x; rr[7] -= alpha*q3.y;
    }

    if (it != SPAR - 1) {
      // f32 Gram recursion (atom-mapped), 2 sigs per batch (register-lean)
#pragma unroll
      for (int sb = 0; sb < 8; sb += 2) {
        int   g0i = __shfl(bgi, sb << 3);
        float a0f = (float)__shfl(alpha, sb << 3);
        int   g1i = __shfl(bgi, (sb + 1) << 3);
        float a1f = (float)__shfl(alpha, (sb + 1) << 3);
        const float* gp0 = G32 + (size_t)g0i * NATOM + abase;
        const float* gp1 = G32 + (size_t)g1i * NATOM + abase;
        float4 u0 = *(const float4*)gp0;
        float4 u1 = *(const float4*)(gp0 + 4);
        float4 v0 = *(const float4*)gp1;
        float4 v1 = *(const float4*)(gp1 + 4);
        cor[0][sb] -= a0f*u0.x; cor[1][sb] -= a0f*u0.y;
        cor[2][sb] -= a0f*u0.z; cor[3][sb] -= a0f*u0.w;
        cor[4][sb] -= a0f*u1.x; cor[5][sb] -= a0f*u1.y;
        cor[6][sb] -= a0f*u1.z; cor[7][sb] -= a0f*u1.w;
        cor[0][sb+1] -= a1f*v0.x; cor[1][sb+1] -= a1f*v0.y;
        cor[2][sb+1] -= a1f*v0.z; cor[3][sb+1] -= a1f*v0.w;
        cor[4][sb+1] -= a1f*v1.x; cor[5][sb+1] -= a1f*v1.y;
        cor[6][sb+1] -= a1f*v1.z; cor[7][sb+1] -= a1f*v1.w;
      }
    }
  }
  __syncthreads();                         // publish s_sel/s_al; xs reads done

  // ---- epilogue A: zv = f32(x - rr) into xs (own slots, swizzled) + loss ----
  {
    double s2 = 0.0;
    const int d0 = lg << 3;
#pragma unroll
    for (int j = 0; j < 8; ++j) {
      int idx = SW((d0 + j) * 32 + sig);
      double x = (double)xs[idx];
      float zv = (float)(x - rr[j]);
      xs[idx] = zv;                        // single-owner slot, no race
      double diff = (double)zv - x;
      s2 += diff * diff;
    }
#pragma unroll
    for (int o = 1; o < 64; o <<= 1) s2 += __shfl_xor(s2, o);
    if (lane == 0) s_red[w] = s2;
  }

  // ---- epilogue B part 1: coeff zero-fill (coalesced 128B runs) ----
  {
    const float4 z4 = make_float4(0.f, 0.f, 0.f, 0.f);
#pragma unroll
    for (int p2 = 0; p2 < 16; ++p2) {
      int idx = tid + (p2 << 8);           // 0..4095 = atom*8 + quad
      int a = idx >> 3, q = idx & 7;
      *(float4*)(coeff + (size_t)a * NSIG + ((size_t)l << 5) + (q << 2)) = z4;
    }
  }
  __syncthreads();                         // zv in xs ready; zeros ordered

  // ---- epilogue C: coalesced zv write-back (swizzled src) ----
  {
    float* dst = xw + (size_t)l * 2048;
#pragma unroll
    for (int p = 0; p < 2; ++p)
      *(float4*)(dst + tid * 4 + p * 1024) = *(const float4*)&xs[SW(tid * 4 + p * 1024)];
  }
  if (tid == 0) partial[bid] = (s_red[0] + s_red[1]) + (s_red[2] + s_red[3]);
  if (tid < 32) {
#pragma unroll
    for (int tt = 0; tt < SPAR; ++tt) {
      int gi = s_sel[tt][tid];
      coeff[(size_t)gi * NSIG + ((size_t)l << 5) + tid] = (float)s_al[tt][tid];
    }
  }
}

// ---- fused: unpack (bid<2048) | finalize loss (bid==2048) -------------------
__global__ __launch_bounds__(256) void unpack_fin_kernel(const float* __restrict__ xw,
                                                         float* __restrict__ z_dl,
                                                         const double* __restrict__ partial,
                                                         float* __restrict__ loss_out) {
  __shared__ float t[32][33];
  const int bid = blockIdx.x;
  if (bid < 2048) {
    const int c  = bid & 63;
    const int l0 = (bid >> 6) << 5;
    const int tr = threadIdx.x >> 5;       // 0..7
    const int tc = threadIdx.x & 31;
#pragma unroll
    for (int p = 0; p < 4; ++p) {
      int lr = tr + p * 8;                 // read coalesced in b (=tc)
      t[lr][tc] = xw[(size_t)(l0 + lr) * 2048 + c * 32 + tc];
    }
    __syncthreads();
#pragma unroll
    for (int p = 0; p < 4; ++p) {
      int b = tr + p * 8;                  // write coalesced in l (=tc)
      z_dl[(size_t)b * 65536 + (size_t)c * 1024 + l0 + tc] = t[tc][b];
    }
  } else if (threadIdx.x < 64) {
    double s = 0.0;
    for (int i = threadIdx.x; i < 1024; i += 64) s += partial[i];
#pragma unroll
    for (int o = 32; o > 0; o >>= 1) s += __shfl_down(s, o);
    if (threadIdx.x == 0) loss_out[0] = (float)(1.25 * s / 2097152.0);
  }
}

extern "C" void kernel_launch(void* const* d_in, const int* in_sizes, int n_in,
                              void* d_out, int out_size, void* d_ws, size_t ws_size,
                              hipStream_t stream) {
  const float* z_e = (const float*)d_in[0];
  const float* D   = (const float*)d_in[1];

  float* out      = (float*)d_out;
  float* z_dl     = out;                       // 2097152 elems
  float* loss_out = out + 2097152;             // 1 elem
  float* coeff    = out + 2097153;             // 512*32768 elems

  char*   ws      = (char*)d_ws;
  double* partial = (double*)ws;                               // 8 KiB (1024)
  float*  Dt32    = (float*) (ws + 8192);                      // 128 KiB
  double* Dd64    = (double*)(ws + 8192 + 131072);             // 256 KiB
  double* rnrm    = (double*)(ws + 8192 + 131072 + 262144);    // 4 KiB
  float*  G32     = (float*) (ws + 8192 + 131072 + 262144 + 4096);           // 1 MiB
  float*  xw      = (float*) (ws + 8192 + 131072 + 262144 + 4096 + 1048576); // 8 MiB

  prep_kernel<<<8, 64, 0, stream>>>(D, Dt32, Dd64, rnrm);
  gram_repack_kernel<<<2560, 256, 0, stream>>>(z_e, xw, Dt32, G32);
  omp12_kernel<<<1024, 256, 0, stream>>>(xw, Dt32, Dd64, rnrm, G32, coeff, partial);
  unpack_fin_kernel<<<2049, 256, 0, stream>>>(xw, z_dl, partial, loss_out);
}